// Round 12
// baseline (37.756 us; speedup 1.0000x reference)
//
#include <hip/hip_runtime.h>

// ChamferDistance: B=4, N=M=8192, fp32 3-D points.
// R12: tile-pair v_min3 reduction + 8-reg double-buffered load pipeline on
// the barrier-free streaming structure.
// R11 post-mortem: depth-4 pipeline changed nothing (37.1 vs 37.8) — load
// latency is NOT the binding constraint. Attack the largest static cost
// instead: 32 fmin/tile -> 16 min3 per tile PAIR (VALU floor 6.8 -> 3.4 µs).
// R6-R8's pairing spilled at the 128-reg cap with 4 live accs; here acc-pairs
// are produced/consumed one row-tile at a time: live set ~116 regs
// (afrag 8 + bf[8] 32 + rmin 32 + acc pair 32 + addr) fits (256,4).
// Math unchanged (verified since R4, absmax 0.0156).

typedef short  short8 __attribute__((ext_vector_type(8)));
typedef float  f32x16 __attribute__((ext_vector_type(16)));

#define B_      4
#define NPT     8192
#define THREADS 256
#define ROWBLK  32               // 256-row blocks per (pass, batch)
#define NCHUNK  4                // col chunks -> grid = 2*4*32*4 = 1024 = 4/CU
#define CCOLS   (NPT / NCHUNK)   // 2048 cols per chunk
#define NTILE   (CCOLS / 32)     // 64 32-col tiles per chunk
#define PINF_I  0x7f800000

__device__ __forceinline__ unsigned short f2bf(float x) {
    unsigned u = __float_as_uint(x);
    u += 0x7fff + ((u >> 16) & 1);
    return (unsigned short)(u >> 16);
}
__device__ __forceinline__ float bf2f(unsigned short b) {
    return __uint_as_float(((unsigned)b) << 16);
}
#define PK2(a, b) ((((unsigned)(b)) << 16) | (unsigned)(a))

__global__ __launch_bounds__(THREADS)
void cd_pack(const float* __restrict__ xyz1, const float* __restrict__ xyz2,
             unsigned short* __restrict__ A1, unsigned short* __restrict__ B1,
             unsigned short* __restrict__ A2, unsigned short* __restrict__ B2,
             int* __restrict__ out) {
    int i = blockIdx.x * THREADS + threadIdx.x;
    if (i >= B_ * NPT) return;
    const unsigned short one = 0x3f80;

    // B-form split-K placement: group g = i>>5, slot = i&31.
    //   uint4 idx for k0..7  : g*64 + slot ; k8..15 : g*64 + 32 + slot
    const size_t bidx = ((size_t)(i >> 5)) * 64 + (i & 31);

    {   // cloud 1 -> A1 (linear) + B1 (split-K)
        float x0 = xyz1[3*i], x1 = xyz1[3*i+1], x2 = xyz1[3*i+2];
        unsigned short h0 = f2bf(x0), h1 = f2bf(x1), h2 = f2bf(x2);
        unsigned short l0 = f2bf(x0 - bf2f(h0)), l1 = f2bf(x1 - bf2f(h1)), l2 = f2bf(x2 - bf2f(h2));
        unsigned short m0 = f2bf(-2.f * bf2f(h0)), m1 = f2bf(-2.f * bf2f(h1)), m2 = f2bf(-2.f * bf2f(h2));
        unsigned short q0 = f2bf(-2.f * bf2f(l0)), q1 = f2bf(-2.f * bf2f(l1)), q2 = f2bf(-2.f * bf2f(l2));
        float n = x0*x0 + x1*x1 + x2*x2;
        unsigned short nh = f2bf(n), nl = f2bf(n - bf2f(nh));
        ((uint4*)A1)[(size_t)i * 2]     = make_uint4(PK2(m0, m1), PK2(m2, q0), PK2(q1, q2), PK2(m0, m1));
        ((uint4*)A1)[(size_t)i * 2 + 1] = make_uint4(PK2(m2, nh), PK2(nl, one), PK2(one, 0), PK2(0, 0));
        ((uint4*)B1)[bidx]      = make_uint4(PK2(h0, h1), PK2(h2, h0), PK2(h1, h2), PK2(l0, l1));
        ((uint4*)B1)[bidx + 32] = make_uint4(PK2(l2, one), PK2(one, nh), PK2(nl, 0), PK2(0, 0));
    }
    {   // cloud 2 -> A2 (linear) + B2 (split-K)
        float x0 = xyz2[3*i], x1 = xyz2[3*i+1], x2 = xyz2[3*i+2];
        unsigned short h0 = f2bf(x0), h1 = f2bf(x1), h2 = f2bf(x2);
        unsigned short l0 = f2bf(x0 - bf2f(h0)), l1 = f2bf(x1 - bf2f(h1)), l2 = f2bf(x2 - bf2f(h2));
        unsigned short m0 = f2bf(-2.f * bf2f(h0)), m1 = f2bf(-2.f * bf2f(h1)), m2 = f2bf(-2.f * bf2f(h2));
        unsigned short q0 = f2bf(-2.f * bf2f(l0)), q1 = f2bf(-2.f * bf2f(l1)), q2 = f2bf(-2.f * bf2f(l2));
        float n = x0*x0 + x1*x1 + x2*x2;
        unsigned short nh = f2bf(n), nl = f2bf(n - bf2f(nh));
        ((uint4*)A2)[(size_t)i * 2]     = make_uint4(PK2(m0, m1), PK2(m2, q0), PK2(q1, q2), PK2(m0, m1));
        ((uint4*)A2)[(size_t)i * 2 + 1] = make_uint4(PK2(m2, nh), PK2(nl, one), PK2(one, 0), PK2(0, 0));
        ((uint4*)B2)[bidx]      = make_uint4(PK2(h0, h1), PK2(h2, h0), PK2(h1, h2), PK2(l0, l1));
        ((uint4*)B2)[bidx + 32] = make_uint4(PK2(l2, one), PK2(one, nh), PK2(nl, 0), PK2(0, 0));
    }
    out[i] = PINF_I;
    out[(size_t)B_ * NPT + i] = PINF_I;
}

// Pair-compute on two B tiles: row-tile 0's acc pair is produced and fully
// consumed (min3) before row-tile 1's — keeps one 32-reg acc pair live.
#define CD_PAIR(bx, by)                                                          \
    {                                                                            \
        f32x16 z = {0.f};                                                        \
        f32x16 accX = __builtin_amdgcn_mfma_f32_32x32x16_bf16(afrag0, bx, z, 0, 0, 0); \
        f32x16 accY = __builtin_amdgcn_mfma_f32_32x32x16_bf16(afrag0, by, z, 0, 0, 0); \
        _Pragma("unroll")                                                        \
        for (int r = 0; r < 16; ++r)                                             \
            rmin0[r] = fminf(fminf(accX[r], accY[r]), rmin0[r]);                 \
        accX = __builtin_amdgcn_mfma_f32_32x32x16_bf16(afrag1, bx, z, 0, 0, 0);  \
        accY = __builtin_amdgcn_mfma_f32_32x32x16_bf16(afrag1, by, z, 0, 0, 0);  \
        _Pragma("unroll")                                                        \
        for (int r = 0; r < 16; ++r)                                             \
            rmin1[r] = fminf(fminf(accX[r], accY[r]), rmin1[r]);                 \
    }

// Reload one bf register with tile index tn (clamped to the last tile; the
// tail re-reads tile 63 harmlessly — min is idempotent).
#define CD_LOAD(bf, tn)                                                          \
    {                                                                            \
        int tt = (tn) < NTILE ? (tn) : NTILE - 1;                                \
        bf = *(const short8*)(gB + (size_t)tt * 512);                            \
    }

__global__ __launch_bounds__(THREADS, 4)    // live ~116 regs < 128 cap
void cd_mfma32(const unsigned short* __restrict__ A1, const unsigned short* __restrict__ B1,
               const unsigned short* __restrict__ A2, const unsigned short* __restrict__ B2,
               int* __restrict__ out) {
    int bid = blockIdx.x;
    const int c    = bid & (NCHUNK - 1);  bid >>= 2;
    const int rb   = bid & (ROWBLK - 1);  bid >>= 5;
    const int b    = bid & (B_ - 1);      bid >>= 2;
    const int pass = bid;                               // 0: dist1, 1: dist2

    const unsigned short* __restrict__ Ap = pass ? A2 : A1;
    const unsigned short* __restrict__ Bp = pass ? B1 : B2;
    int* __restrict__ o = out + (size_t)pass * B_ * NPT;

    const int lane = threadIdx.x & 63;
    const int w    = threadIdx.x >> 6;
    const int l31  = lane & 31;
    const int kg   = lane >> 5;            // k-half: k = kg*8 + idx

    const size_t bbase   = (size_t)b * NPT;
    const int    rowBase = rb * 256 + w * 64;

    // A fragments (linear layout), resident for the whole sweep
    short8 afrag0 = *(const short8*)(Ap + (bbase + rowBase +  0 + l31) * 16 + kg * 8);
    short8 afrag1 = *(const short8*)(Ap + (bbase + rowBase + 32 + l31) * 16 + kg * 8);

    f32x16 rmin0, rmin1;
    #pragma unroll
    for (int r = 0; r < 16; ++r) {
        rmin0[r] = __int_as_float(PINF_I);
        rmin1[r] = __int_as_float(PINF_I);
    }

    // B chunk base, split-K: 32-pt group = 512 ushorts; lane reads
    // kg*256 + l31*8 -> each wave instruction covers a contiguous 1 KB.
    const unsigned short* __restrict__ gB =
        Bp + (bbase + (size_t)c * CCOLS) * 16 + kg * 256 + l31 * 8;

    // Prime 8 tiles in flight (two 4-tile banks)
    short8 bf0, bf1, bf2, bf3, bf4, bf5, bf6, bf7;
    CD_LOAD(bf0, 0) CD_LOAD(bf1, 1) CD_LOAD(bf2, 2) CD_LOAD(bf3, 3)
    CD_LOAD(bf4, 4) CD_LOAD(bf5, 5) CD_LOAD(bf6, 6) CD_LOAD(bf7, 7)

    // Steady state: compute a 2-tile pair, then reload those regs for t+8.
    // Consume-after-load distance = 3 pair-phases (~300+ cyc) > L2 latency.
    for (int t = 0; t < NTILE; t += 8) {
        CD_PAIR(bf0, bf1)
        CD_LOAD(bf0, t + 8)  CD_LOAD(bf1, t + 9)
        CD_PAIR(bf2, bf3)
        CD_LOAD(bf2, t + 10) CD_LOAD(bf3, t + 11)
        CD_PAIR(bf4, bf5)
        CD_LOAD(bf4, t + 12) CD_LOAD(bf5, t + 13)
        CD_PAIR(bf6, bf7)
        CD_LOAD(bf6, t + 14) CD_LOAD(bf7, t + 15)
    }

    // Epilogue: butterfly row-mins across 32 col-slots, one atomic per row
    #pragma unroll
    for (int rt = 0; rt < 2; ++rt) {
        #pragma unroll
        for (int r = 0; r < 16; ++r) {
            float v = rt ? rmin1[r] : rmin0[r];
            v = fminf(v, __shfl_xor(v, 1, 64));
            v = fminf(v, __shfl_xor(v, 2, 64));
            v = fminf(v, __shfl_xor(v, 4, 64));
            v = fminf(v, __shfl_xor(v, 8, 64));
            v = fminf(v, __shfl_xor(v, 16, 64));
            if (l31 == 0) {
                int row = rowBase + rt * 32 + (r & 3) + 8 * (r >> 2) + 4 * kg;
                atomicMin(&o[bbase + row], __float_as_int(fmaxf(v, 0.f)));
            }
        }
    }
}

extern "C" void kernel_launch(void* const* d_in, const int* in_sizes, int n_in,
                              void* d_out, int out_size, void* d_ws, size_t ws_size,
                              hipStream_t stream) {
    const float* xyz1 = (const float*)d_in[0];
    const float* xyz2 = (const float*)d_in[1];

    const size_t PSZ = (size_t)B_ * NPT * 16;       // ushorts per packed array
    unsigned short* A1 = (unsigned short*)d_ws;     // 4 x 1 MB in d_ws
    unsigned short* B1 = A1 + PSZ;
    unsigned short* A2 = B1 + PSZ;
    unsigned short* B2 = A2 + PSZ;

    cd_pack<<<(B_ * NPT + THREADS - 1) / THREADS, THREADS, 0, stream>>>(
        xyz1, xyz2, A1, B1, A2, B2, (int*)d_out);

    cd_mfma32<<<2 * B_ * ROWBLK * NCHUNK, THREADS, 0, stream>>>(
        A1, B1, A2, B2, (int*)d_out);
}